// Round 2
// baseline (722.576 us; speedup 1.0000x reference)
//
#include <hip/hip_runtime.h>
#include <hip/hip_bf16.h>

typedef __attribute__((ext_vector_type(8))) short bf16x8;   // 8 bf16 in 4 VGPRs
typedef __attribute__((ext_vector_type(4))) float f32x4;

#define DEV __device__ __forceinline__

DEV float fsigmoid(float x){ return 1.0f/(1.0f + __expf(-x)); }
DEV float fsilu(float x){ return x/(1.0f + __expf(-x)); }
DEV float ftanh(float x){ return 1.0f - 2.0f/(1.0f + __expf(2.0f*x)); }

DEV unsigned short f2bf(float x){
  __hip_bfloat16 h = __float2bfloat16(x);
  return *reinterpret_cast<unsigned short*>(&h);
}
DEV float bf2f(unsigned short u){ return __uint_as_float(((unsigned)u) << 16); }

typedef const __attribute__((address_space(1))) unsigned int* gas_ptr;
typedef __attribute__((address_space(3))) unsigned int* las_ptr;
// async global->LDS, 16B/lane; LDS dest = wave-uniform base, HW adds lane*16.
DEV void gload16(const void* gp, void* lp){
  __builtin_amdgcn_global_load_lds((gas_ptr)gp, (las_ptr)lp, 16, 0, 0);
}

// ---------------- conversion kernels ----------------

__global__ __launch_bounds__(256) void k_conv_x(const float* __restrict__ src, __hip_bfloat16* __restrict__ dst){
  size_t gid = (size_t)blockIdx.x*256 + threadIdx.x;
  size_t base = gid*8;
  f32x4 a = *(const f32x4*)(src+base);
  f32x4 b = *(const f32x4*)(src+base+4);
  bf16x8 o;
#pragma unroll
  for(int j=0;j<4;j++){ o[j]=(short)f2bf(a[j]); o[4+j]=(short)f2bf(b[j]); }
  *(bf16x8*)((unsigned short*)dst + base) = o;
}

// W1 rows: [0:2048)=W_forget, [2048:4096)=W_query, [4096:6144)=W_input,
//          [6144:8192)=W_value, [8192:10240)=W_up, [10240:12288)=W_gate
__global__ __launch_bounds__(256) void k_conv_w1(const float* __restrict__ Wf,const float* __restrict__ Wq,
    const float* __restrict__ Wi,const float* __restrict__ Wv,const float* __restrict__ Wu,
    const float* __restrict__ Wg, __hip_bfloat16* __restrict__ W1){
  int gid = blockIdx.x*256 + threadIdx.x;
  int row = gid>>7; int col = (gid&127)*8;
  int seg = row>>11; int sr = row & 2047;
  const float* s;
  if(seg==0)s=Wf; else if(seg==1)s=Wq; else if(seg==2)s=Wi; else if(seg==3)s=Wv; else if(seg==4)s=Wu; else s=Wg;
  const float* p = s + (size_t)sr*1024 + col;
  f32x4 a = *(const f32x4*)p; f32x4 b = *(const f32x4*)(p+4);
  bf16x8 o;
#pragma unroll
  for(int j=0;j<4;j++){ o[j]=(short)f2bf(a[j]); o[4+j]=(short)f2bf(b[j]); }
  *(bf16x8*)((unsigned short*)W1 + (size_t)row*1024 + col) = o;
}

// W2 [1024][4096]: cols [0:2048)=W_rec_out row, [2048:4096)=W_down row
__global__ __launch_bounds__(256) void k_conv_w2(const float* __restrict__ Wro, const float* __restrict__ Wd,
    __hip_bfloat16* __restrict__ W2){
  int gid = blockIdx.x*256 + threadIdx.x;
  int row = gid>>9; int col = (gid&511)*8;
  const float* p = (col<2048) ? (Wro + (size_t)row*2048 + col) : (Wd + (size_t)row*2048 + (col-2048));
  f32x4 a = *(const f32x4*)p; f32x4 b = *(const f32x4*)(p+4);
  bf16x8 o;
#pragma unroll
  for(int j=0;j<4;j++){ o[j]=(short)f2bf(a[j]); o[4+j]=(short)f2bf(b[j]); }
  *(bf16x8*)((unsigned short*)W2 + (size_t)row*4096 + col) = o;
}

// ---------------- GEMM1: [Mc,1024] x [12288,1024]^T, activation epilogue ----------------
// m97 structure: 128x128 tile, BK=32, 4 waves (2x2), 16x16x32 bf16 MFMA, global_load_lds w16.

__global__ __launch_bounds__(256) void k_gemm1(const __hip_bfloat16* __restrict__ A, const __hip_bfloat16* __restrict__ B,
    float* __restrict__ fb, float* __restrict__ gb, float* __restrict__ cb,
    __hip_bfloat16* __restrict__ qb, __hip_bfloat16* __restrict__ upg){
  const int K = 1024;
  __shared__ __hip_bfloat16 sA[128*32];
  __shared__ __hip_bfloat16 sB[128*32];
  int bid = blockIdx.x;
  int cpx = gridDim.x >> 3;                // grid % 8 == 0 in all CB configs
  bid = (bid & 7)*cpx + (bid >> 3);        // bijective XCD swizzle
  int bm = bid/96, bn = bid%96;
  int t = threadIdx.x, w = t>>6, lane = t&63;
  int wr = w>>1, wc = w&1;

  f32x4 zero = {0.f,0.f,0.f,0.f};
  f32x4 acc[4][4];
#pragma unroll
  for(int i=0;i<4;i++)
#pragma unroll
    for(int j=0;j<4;j++) acc[i][j] = zero;

  const int frow = lane&15;
  const int kofs = (lane>>4)*8;
  const unsigned short* Ag = (const unsigned short*)A;
  const unsigned short* Bg = (const unsigned short*)B;

  for(int kt=0; kt<K; kt+=32){
#pragma unroll
    for(int i=0;i<2;i++){
      int c = i*256 + t;
      gload16(Ag + (size_t)(bm*128 + (c>>2))*K + kt + (c&3)*8, (char*)sA + (i*256 + w*64)*16);
      gload16(Bg + (size_t)(bn*128 + (c>>2))*K + kt + (c&3)*8, (char*)sB + (i*256 + w*64)*16);
    }
    __syncthreads();
    bf16x8 af[4], bfr[4];
#pragma unroll
    for(int mi=0;mi<4;mi++) af[mi]  = *(const bf16x8*)&sA[(wr*64 + mi*16 + frow)*32 + kofs];
#pragma unroll
    for(int ni=0;ni<4;ni++) bfr[ni] = *(const bf16x8*)&sB[(wc*64 + ni*16 + frow)*32 + kofs];
#pragma unroll
    for(int mi=0;mi<4;mi++)
#pragma unroll
      for(int ni=0;ni<4;ni++)
        acc[mi][ni] = __builtin_amdgcn_mfma_f32_16x16x32_bf16(af[mi], bfr[ni], acc[mi][ni], 0,0,0);
    __syncthreads();
  }

  // epilogue: C/D layout col=lane&15, row=(lane>>4)*4+j  [m89-verified]
  int seg = bn/16;                                  // 16 n-tiles per 2048-col segment
  int row0 = bm*128 + wr*64 + ((lane>>4)<<2);
  int colL = ((bn*128)&2047) + wc*64 + (lane&15);

#define EPI(STMT) \
  _Pragma("unroll") for(int mi=0;mi<4;mi++) \
  _Pragma("unroll") for(int ni=0;ni<4;ni++) \
  _Pragma("unroll") for(int j=0;j<4;j++) { \
    int rr=row0+mi*16+j; int cc=colL+ni*16; float v=acc[mi][ni][j]; STMT; }

  if(seg==0)      { EPI( fb[(size_t)rr*2048+cc] = ftanh(v) ) }
  else if(seg==1) { EPI( qb[(size_t)rr*2048+cc] = __float2bfloat16(v) ) }
  else if(seg==2) { EPI( gb[(size_t)rr*2048+cc] = fsigmoid(v) ) }
  else if(seg==3) { EPI( cb[(size_t)rr*2048+cc] = fsilu(v) ) }
  else if(seg==4) { EPI( upg[(size_t)rr*4096+cc] = __float2bfloat16(v) ) }
  else            { EPI( upg[(size_t)rr*4096+2048+cc] = __float2bfloat16(fsilu(v)) ) }
#undef EPI
}

// ---------------- scan: 3-pass chunked diagonal recurrence ----------------
#define NC 64
#define CHL 32

__global__ __launch_bounds__(256) void k_scanA(const float* __restrict__ f_, const float* __restrict__ g_,
    const float* __restrict__ c_, float* __restrict__ Fp_, float* __restrict__ Sl_){
  int blk = blockIdx.x; int b = blk>>6; int ch = blk&63;   // b chunk-local
  int r0 = threadIdx.x*8;
  float st[8], Fp[8];
#pragma unroll
  for(int j=0;j<8;j++){ st[j]=0.f; Fp[j]=1.f; }
  size_t base = ((size_t)(b*2048 + ch*CHL))*2048 + r0;
#pragma unroll 4
  for(int s=0;s<CHL;s++){
    size_t o = base + (size_t)s*2048;
    float fv[8], gv[8], cv[8];
    *(f32x4*)&fv[0]=*(const f32x4*)(f_+o); *(f32x4*)&fv[4]=*(const f32x4*)(f_+o+4);
    *(f32x4*)&gv[0]=*(const f32x4*)(g_+o); *(f32x4*)&gv[4]=*(const f32x4*)(g_+o+4);
    *(f32x4*)&cv[0]=*(const f32x4*)(c_+o); *(f32x4*)&cv[4]=*(const f32x4*)(c_+o+4);
#pragma unroll
    for(int j=0;j<8;j++){ st[j] = fv[j]*st[j] + gv[j]*cv[j]; Fp[j] *= fv[j]; }
  }
  size_t so = ((size_t)blk)*2048 + r0;
  *(f32x4*)(Fp_+so)   = *(f32x4*)&Fp[0]; *(f32x4*)(Fp_+so+4) = *(f32x4*)&Fp[4];
  *(f32x4*)(Sl_+so)   = *(f32x4*)&st[0]; *(f32x4*)(Sl_+so+4) = *(f32x4*)&st[4];
}

__global__ __launch_bounds__(256) void k_scanB(const float* __restrict__ Fp_, const float* __restrict__ Sl_,
    const float* __restrict__ init, float* __restrict__ Cin_){
  int gid = blockIdx.x*256 + threadIdx.x;   // CB*2048 threads
  int b = gid>>11; int r = gid&2047;
  float carry = init[r];
  for(int ch=0; ch<NC; ch++){
    size_t o = ((size_t)(b*NC+ch))*2048 + r;
    Cin_[o] = carry;
    carry = Fp_[o]*carry + Sl_[o];
  }
}

// q read (bf16) and readout write share the SAME buffer (qro): element o is read
// then overwritten by the same thread — race-free; no __restrict__ on qro.
__global__ __launch_bounds__(256) void k_scanC(const float* __restrict__ f_, const float* __restrict__ g_,
    const float* __restrict__ c_, unsigned short* qro, const float* __restrict__ Cin_){
  int blk = blockIdx.x; int b = blk>>6; int ch = blk&63;
  int r0 = threadIdx.x*8;
  float st[8];
  size_t so = ((size_t)blk)*2048 + r0;
  *(f32x4*)&st[0] = *(const f32x4*)(Cin_+so);
  *(f32x4*)&st[4] = *(const f32x4*)(Cin_+so+4);
  size_t base = ((size_t)(b*2048 + ch*CHL))*2048 + r0;
#pragma unroll 2
  for(int s=0;s<CHL;s++){
    size_t o = base + (size_t)s*2048;
    float fv[8], gv[8], cv[8];
    *(f32x4*)&fv[0]=*(const f32x4*)(f_+o); *(f32x4*)&fv[4]=*(const f32x4*)(f_+o+4);
    *(f32x4*)&gv[0]=*(const f32x4*)(g_+o); *(f32x4*)&gv[4]=*(const f32x4*)(g_+o+4);
    *(f32x4*)&cv[0]=*(const f32x4*)(c_+o); *(f32x4*)&cv[4]=*(const f32x4*)(c_+o+4);
    bf16x8 qu = *(const bf16x8*)(qro + o);
    bf16x8 ov;
#pragma unroll
    for(int j=0;j<8;j++){
      st[j] = fv[j]*st[j] + gv[j]*cv[j];
      float qv = bf2f((unsigned short)qu[j]);
      ov[j] = (short)f2bf(fsilu(qv*st[j]));
    }
    *(bf16x8*)(qro + o) = ov;
  }
}

// ---------------- elementwise: ug = up * silu(gate) (silu applied in epilogue), overwrite up half ----------------
__global__ __launch_bounds__(256) void k_ew_ug(__hip_bfloat16* __restrict__ upg){
  size_t gid = (size_t)blockIdx.x*256 + threadIdx.x;
  size_t m = gid>>8; size_t l0 = (gid&255)*8;
  unsigned short* p = (unsigned short*)upg;
  bf16x8 uv = *(const bf16x8*)(p + m*4096 + l0);
  bf16x8 gv = *(const bf16x8*)(p + m*4096 + 2048 + l0);
  bf16x8 ov;
#pragma unroll
  for(int j=0;j<8;j++){
    float u = bf2f((unsigned short)uv[j]);
    float g = bf2f((unsigned short)gv[j]);
    ov[j] = (short)f2bf(u*g);
  }
  *(bf16x8*)(p + m*4096 + l0) = ov;
}

// ---------------- GEMM2: [Mc, 4096(readout|ug)] x [1024,4096]^T -> out fp32 ----------------
__global__ __launch_bounds__(256) void k_gemm2(const __hip_bfloat16* __restrict__ RO, const __hip_bfloat16* __restrict__ UPG,
    const __hip_bfloat16* __restrict__ B, float* __restrict__ out){
  __shared__ __hip_bfloat16 sA[128*32];
  __shared__ __hip_bfloat16 sB[128*32];
  int bid = blockIdx.x;
  int cpx = gridDim.x >> 3;
  bid = (bid & 7)*cpx + (bid >> 3);
  int bm = bid>>3, bn = bid&7;
  int t = threadIdx.x, w = t>>6, lane = t&63;
  int wr = w>>1, wc = w&1;

  f32x4 zero = {0.f,0.f,0.f,0.f};
  f32x4 acc[4][4];
#pragma unroll
  for(int i=0;i<4;i++)
#pragma unroll
    for(int j=0;j<4;j++) acc[i][j] = zero;

  const int frow = lane&15;
  const int kofs = (lane>>4)*8;
  const unsigned short* ROg  = (const unsigned short*)RO;
  const unsigned short* UPGg = (const unsigned short*)UPG;
  const unsigned short* Bg   = (const unsigned short*)B;

  for(int kt=0; kt<4096; kt+=32){
    const unsigned short* Abase; size_t ld; int kk;
    if(kt < 2048){ Abase = ROg;  ld = 2048; kk = kt; }
    else         { Abase = UPGg; ld = 4096; kk = kt - 2048; }
#pragma unroll
    for(int i=0;i<2;i++){
      int c = i*256 + t;
      gload16(Abase + (size_t)(bm*128 + (c>>2))*ld + kk + (c&3)*8, (char*)sA + (i*256 + w*64)*16);
      gload16(Bg + (size_t)(bn*128 + (c>>2))*4096 + kt + (c&3)*8, (char*)sB + (i*256 + w*64)*16);
    }
    __syncthreads();
    bf16x8 af[4], bfr[4];
#pragma unroll
    for(int mi=0;mi<4;mi++) af[mi]  = *(const bf16x8*)&sA[(wr*64 + mi*16 + frow)*32 + kofs];
#pragma unroll
    for(int ni=0;ni<4;ni++) bfr[ni] = *(const bf16x8*)&sB[(wc*64 + ni*16 + frow)*32 + kofs];
#pragma unroll
    for(int mi=0;mi<4;mi++)
#pragma unroll
      for(int ni=0;ni<4;ni++)
        acc[mi][ni] = __builtin_amdgcn_mfma_f32_16x16x32_bf16(af[mi], bfr[ni], acc[mi][ni], 0,0,0);
    __syncthreads();
  }

  int row0 = bm*128 + wr*64 + ((lane>>4)<<2);
  int col0 = bn*128 + wc*64 + (lane&15);
#pragma unroll
  for(int mi=0;mi<4;mi++)
#pragma unroll
    for(int ni=0;ni<4;ni++)
#pragma unroll
      for(int j=0;j<4;j++)
        out[(size_t)(row0+mi*16+j)*1024 + col0 + ni*16] = acc[mi][ni][j];
}

// ---------------- launcher ----------------
extern "C" void kernel_launch(void* const* d_in, const int* in_sizes, int n_in,
                              void* d_out, int out_size, void* d_ws, size_t ws_size,
                              hipStream_t stream) {
  (void)in_sizes; (void)n_in; (void)out_size;
  const float* x   = (const float*)d_in[0];
  const float* Wf  = (const float*)d_in[1];
  const float* Wi  = (const float*)d_in[2];
  const float* Wv  = (const float*)d_in[3];
  const float* Wq  = (const float*)d_in[4];
  const float* Wro = (const float*)d_in[5];
  const float* Wu  = (const float*)d_in[6];
  const float* Wg  = (const float*)d_in[7];
  const float* Wd  = (const float*)d_in[8];
  const float* ist = (const float*)d_in[9];
  float* out = (float*)d_out;

  char* w = (char*)d_ws;
  auto alloc = [&](size_t bytes){ char* p = w; w += (bytes + 255) & ~(size_t)255; return p; };

  // fixed buffers (needed across the whole pipeline)
  __hip_bfloat16* xb = (__hip_bfloat16*)alloc(16777216);   // [8192][1024] bf16
  __hip_bfloat16* W1 = (__hip_bfloat16*)alloc(25165824);   // [12288][1024] bf16
  __hip_bfloat16* W2 = (__hip_bfloat16*)alloc(8388608);    // [1024][4096] bf16

  // choose batch-chunk size CB from available workspace (deterministic per env)
  size_t fixed = (size_t)16777216 + 25165824 + 8388608 + 3*256;
  auto need = [&](int CBq)->size_t{
    return fixed + (size_t)CBq*(3*(size_t)16777216 + 8388608 + 16777216 + 3*524288)
                 + 6*256 + (size_t)(1<<20);
  };
  int CB = (ws_size >= need(4)) ? 4 : (ws_size >= need(2)) ? 2 : 1;

  float* fb = (float*)alloc((size_t)CB*16777216);             // [CB*2048][2048] f32 tanh(f)
  float* gb = (float*)alloc((size_t)CB*16777216);             // sigmoid(g)
  float* cb = (float*)alloc((size_t)CB*16777216);             // silu(c)
  unsigned short* qro = (unsigned short*)alloc((size_t)CB*8388608);  // bf16 q, overwritten by readout
  __hip_bfloat16* upg = (__hip_bfloat16*)alloc((size_t)CB*16777216); // [CB*2048][4096] bf16 up|silu(gate)
  float* Fp = (float*)alloc((size_t)CB*524288);
  float* Sl = (float*)alloc((size_t)CB*524288);
  float* Ci = (float*)alloc((size_t)CB*524288);

  k_conv_x <<<4096, 256, 0, stream>>>(x, xb);
  k_conv_w1<<<6144, 256, 0, stream>>>(Wf, Wq, Wi, Wv, Wu, Wg, W1);
  k_conv_w2<<<2048, 256, 0, stream>>>(Wro, Wd, W2);

  for(int b0 = 0; b0 < 4; b0 += CB){
    k_gemm1<<<CB*16*96, 256, 0, stream>>>(xb + (size_t)b0*2048*1024, W1, fb, gb, cb,
                                          (__hip_bfloat16*)qro, upg);
    k_scanA<<<CB*64,   256, 0, stream>>>(fb, gb, cb, Fp, Sl);
    k_scanB<<<CB*8,    256, 0, stream>>>(Fp, Sl, ist, Ci);
    k_scanC<<<CB*64,   256, 0, stream>>>(fb, gb, cb, qro, Ci);
    k_ew_ug<<<CB*2048, 256, 0, stream>>>(upg);
    k_gemm2<<<CB*16*8, 256, 0, stream>>>((const __hip_bfloat16*)qro, upg, W2,
                                         out + (size_t)b0*2048*1024);
  }
}

// Round 5
// 655.378 us; speedup vs baseline: 1.1025x; 1.1025x over previous
//
#include <hip/hip_runtime.h>
#include <hip/hip_bf16.h>

typedef __attribute__((ext_vector_type(8))) short bf16x8;   // 8 bf16 in 4 VGPRs
typedef __attribute__((ext_vector_type(4))) float f32x4;

#define DEV __device__ __forceinline__

DEV float fsigmoid(float x){ return 1.0f/(1.0f + __expf(-x)); }
DEV float fsilu(float x){ return x/(1.0f + __expf(-x)); }
DEV float ftanh(float x){ return 1.0f - 2.0f/(1.0f + __expf(2.0f*x)); }

DEV unsigned short f2bf(float x){
  __hip_bfloat16 h = __float2bfloat16(x);
  return *reinterpret_cast<unsigned short*>(&h);
}
DEV float bf2f(unsigned short u){ return __uint_as_float(((unsigned)u) << 16); }

typedef const __attribute__((address_space(1))) unsigned int* gas_ptr;
typedef __attribute__((address_space(3))) unsigned int* las_ptr;
// async global->LDS, 16B/lane; LDS dest = wave-uniform base, HW adds lane*16.
DEV void gload16(const void* gp, void* lp){
  __builtin_amdgcn_global_load_lds((gas_ptr)gp, (las_ptr)lp, 16, 0, 0);
}

// ---------------- conversion kernels ----------------

__global__ __launch_bounds__(256) void k_conv_x(const float* __restrict__ src, __hip_bfloat16* __restrict__ dst){
  size_t gid = (size_t)blockIdx.x*256 + threadIdx.x;
  size_t base = gid*8;
  f32x4 a = *(const f32x4*)(src+base);
  f32x4 b = *(const f32x4*)(src+base+4);
  bf16x8 o;
#pragma unroll
  for(int j=0;j<4;j++){ o[j]=(short)f2bf(a[j]); o[4+j]=(short)f2bf(b[j]); }
  *(bf16x8*)((unsigned short*)dst + base) = o;
}

// W1 rows: [0:2048)=W_forget, [2048:4096)=W_query, [4096:6144)=W_input,
//          [6144:8192)=W_value, [8192:10240)=W_up, [10240:12288)=W_gate
__global__ __launch_bounds__(256) void k_conv_w1(const float* __restrict__ Wf,const float* __restrict__ Wq,
    const float* __restrict__ Wi,const float* __restrict__ Wv,const float* __restrict__ Wu,
    const float* __restrict__ Wg, __hip_bfloat16* __restrict__ W1){
  int gid = blockIdx.x*256 + threadIdx.x;
  int row = gid>>7; int col = (gid&127)*8;
  int seg = row>>11; int sr = row & 2047;
  const float* s;
  if(seg==0)s=Wf; else if(seg==1)s=Wq; else if(seg==2)s=Wi; else if(seg==3)s=Wv; else if(seg==4)s=Wu; else s=Wg;
  const float* p = s + (size_t)sr*1024 + col;
  f32x4 a = *(const f32x4*)p; f32x4 b = *(const f32x4*)(p+4);
  bf16x8 o;
#pragma unroll
  for(int j=0;j<4;j++){ o[j]=(short)f2bf(a[j]); o[4+j]=(short)f2bf(b[j]); }
  *(bf16x8*)((unsigned short*)W1 + (size_t)row*1024 + col) = o;
}

// W2 [1024][4096]: cols [0:2048)=W_rec_out row, [2048:4096)=W_down row
__global__ __launch_bounds__(256) void k_conv_w2(const float* __restrict__ Wro, const float* __restrict__ Wd,
    __hip_bfloat16* __restrict__ W2){
  int gid = blockIdx.x*256 + threadIdx.x;
  int row = gid>>9; int col = (gid&511)*8;
  const float* p = (col<2048) ? (Wro + (size_t)row*2048 + col) : (Wd + (size_t)row*2048 + (col-2048));
  f32x4 a = *(const f32x4*)p; f32x4 b = *(const f32x4*)(p+4);
  bf16x8 o;
#pragma unroll
  for(int j=0;j<4;j++){ o[j]=(short)f2bf(a[j]); o[4+j]=(short)f2bf(b[j]); }
  *(bf16x8*)((unsigned short*)W2 + (size_t)row*4096 + col) = o;
}

// ---------------- GEMM1: [Mc,1024] x [12288,1024]^T, activation epilogue ----------------
// m97 structure: 128x128 tile, BK=32, 4 waves (2x2), 16x16x32 bf16 MFMA, global_load_lds w16.
// Block ordering: XCD-chunked + GROUP_M=8 column-major-in-group for L2 locality.

__global__ __launch_bounds__(256) void k_gemm1(const __hip_bfloat16* __restrict__ A, const __hip_bfloat16* __restrict__ B,
    float* __restrict__ fb, __hip_bfloat16* __restrict__ gb, __hip_bfloat16* __restrict__ cb,
    __hip_bfloat16* __restrict__ qb, __hip_bfloat16* __restrict__ upg){
  const int K = 1024;
  __shared__ __hip_bfloat16 sA[128*32];
  __shared__ __hip_bfloat16 sB[128*32];
  const int NBN = 96;
  int raw = blockIdx.x;
  int per = gridDim.x >> 3;                  // grid %8==0 in all CB configs
  int p = (raw & 7)*per + (raw >> 3);        // XCD-contiguous position
  int group = p / (8*NBN);                   // nbm %8==0 for CB in {1,2,4}
  int rem   = p % (8*NBN);
  int bm = group*8 + (rem & 7);              // column-major within 8-row group
  int bn = rem >> 3;
  int t = threadIdx.x, w = t>>6, lane = t&63;
  int wr = w>>1, wc = w&1;

  f32x4 zero = {0.f,0.f,0.f,0.f};
  f32x4 acc[4][4];
#pragma unroll
  for(int i=0;i<4;i++)
#pragma unroll
    for(int j=0;j<4;j++) acc[i][j] = zero;

  const int frow = lane&15;
  const int kofs = (lane>>4)*8;
  const unsigned short* Ag = (const unsigned short*)A;
  const unsigned short* Bg = (const unsigned short*)B;

  for(int kt=0; kt<K; kt+=32){
#pragma unroll
    for(int i=0;i<2;i++){
      int c = i*256 + t;
      gload16(Ag + (size_t)(bm*128 + (c>>2))*K + kt + (c&3)*8, (char*)sA + (i*256 + w*64)*16);
      gload16(Bg + (size_t)(bn*128 + (c>>2))*K + kt + (c&3)*8, (char*)sB + (i*256 + w*64)*16);
    }
    __syncthreads();
    bf16x8 af[4], bfr[4];
#pragma unroll
    for(int mi=0;mi<4;mi++) af[mi]  = *(const bf16x8*)&sA[(wr*64 + mi*16 + frow)*32 + kofs];
#pragma unroll
    for(int ni=0;ni<4;ni++) bfr[ni] = *(const bf16x8*)&sB[(wc*64 + ni*16 + frow)*32 + kofs];
#pragma unroll
    for(int mi=0;mi<4;mi++)
#pragma unroll
      for(int ni=0;ni<4;ni++)
        acc[mi][ni] = __builtin_amdgcn_mfma_f32_16x16x32_bf16(af[mi], bfr[ni], acc[mi][ni], 0,0,0);
    __syncthreads();
  }

  // epilogue: C/D layout col=lane&15, row=(lane>>4)*4+j  [m89-verified]
  int seg = bn/16;                                  // 16 n-tiles per 2048-col segment
  int row0 = bm*128 + wr*64 + ((lane>>4)<<2);
  int colL = ((bn*128)&2047) + wc*64 + (lane&15);

#define EPI(STMT) \
  _Pragma("unroll") for(int mi=0;mi<4;mi++) \
  _Pragma("unroll") for(int ni=0;ni<4;ni++) \
  _Pragma("unroll") for(int j=0;j<4;j++) { \
    int rr=row0+mi*16+j; int cc=colL+ni*16; float v=acc[mi][ni][j]; STMT; }

  if(seg==0)      { EPI( fb[(size_t)rr*2048+cc] = ftanh(v) ) }
  else if(seg==1) { EPI( qb[(size_t)rr*2048+cc] = __float2bfloat16(v) ) }
  else if(seg==2) { EPI( gb[(size_t)rr*2048+cc] = __float2bfloat16(fsigmoid(v)) ) }
  else if(seg==3) { EPI( cb[(size_t)rr*2048+cc] = __float2bfloat16(fsilu(v)) ) }
  else if(seg==4) { EPI( upg[(size_t)rr*4096+cc] = __float2bfloat16(v) ) }
  else            { EPI( upg[(size_t)rr*4096+2048+cc] = __float2bfloat16(fsilu(v)) ) }
#undef EPI
}

// ---------------- scan: 3-pass chunked diagonal recurrence ----------------
#define NC 64
#define CHL 32

__global__ __launch_bounds__(256) void k_scanA(const float* __restrict__ f_, const unsigned short* __restrict__ g_,
    const unsigned short* __restrict__ c_, float* __restrict__ Fp_, float* __restrict__ Sl_){
  int blk = blockIdx.x; int b = blk>>6; int ch = blk&63;   // b chunk-local
  int r0 = threadIdx.x*8;
  float st[8], Fp[8];
#pragma unroll
  for(int j=0;j<8;j++){ st[j]=0.f; Fp[j]=1.f; }
  size_t base = ((size_t)(b*2048 + ch*CHL))*2048 + r0;
#pragma unroll 4
  for(int s=0;s<CHL;s++){
    size_t o = base + (size_t)s*2048;
    float fv[8];
    *(f32x4*)&fv[0]=*(const f32x4*)(f_+o); *(f32x4*)&fv[4]=*(const f32x4*)(f_+o+4);
    bf16x8 gv8 = *(const bf16x8*)(g_+o);
    bf16x8 cv8 = *(const bf16x8*)(c_+o);
#pragma unroll
    for(int j=0;j<8;j++){
      float gc = bf2f((unsigned short)gv8[j]) * bf2f((unsigned short)cv8[j]);
      st[j] = fv[j]*st[j] + gc; Fp[j] *= fv[j];
    }
  }
  size_t so = ((size_t)blk)*2048 + r0;
  *(f32x4*)(Fp_+so)   = *(f32x4*)&Fp[0]; *(f32x4*)(Fp_+so+4) = *(f32x4*)&Fp[4];
  *(f32x4*)(Sl_+so)   = *(f32x4*)&st[0]; *(f32x4*)(Sl_+so+4) = *(f32x4*)&st[4];
}

__global__ __launch_bounds__(256) void k_scanB(const float* __restrict__ Fp_, const float* __restrict__ Sl_,
    const float* __restrict__ init, float* __restrict__ Cin_){
  int gid = blockIdx.x*256 + threadIdx.x;   // CB*2048 threads
  int b = gid>>11; int r = gid&2047;
  float carry = init[r];
  for(int ch=0; ch<NC; ch++){
    size_t o = ((size_t)(b*NC+ch))*2048 + r;
    Cin_[o] = carry;
    carry = Fp_[o]*carry + Sl_[o];
  }
}

// q read (bf16) and readout write share the SAME buffer (qro): element o is read
// then overwritten by the same thread — race-free; no __restrict__ on qro.
__global__ __launch_bounds__(256) void k_scanC(const float* __restrict__ f_, const unsigned short* __restrict__ g_,
    const unsigned short* __restrict__ c_, unsigned short* qro, const float* __restrict__ Cin_){
  int blk = blockIdx.x; int b = blk>>6; int ch = blk&63;
  int r0 = threadIdx.x*8;
  float st[8];
  size_t so = ((size_t)blk)*2048 + r0;
  *(f32x4*)&st[0] = *(const f32x4*)(Cin_+so);
  *(f32x4*)&st[4] = *(const f32x4*)(Cin_+so+4);
  size_t base = ((size_t)(b*2048 + ch*CHL))*2048 + r0;
#pragma unroll 2
  for(int s=0;s<CHL;s++){
    size_t o = base + (size_t)s*2048;
    float fv[8];
    *(f32x4*)&fv[0]=*(const f32x4*)(f_+o); *(f32x4*)&fv[4]=*(const f32x4*)(f_+o+4);
    bf16x8 gv8 = *(const bf16x8*)(g_+o);
    bf16x8 cv8 = *(const bf16x8*)(c_+o);
    bf16x8 qu = *(const bf16x8*)(qro + o);
    bf16x8 ov;
#pragma unroll
    for(int j=0;j<8;j++){
      float gc = bf2f((unsigned short)gv8[j]) * bf2f((unsigned short)cv8[j]);
      st[j] = fv[j]*st[j] + gc;
      float qv = bf2f((unsigned short)qu[j]);
      ov[j] = (short)f2bf(fsilu(qv*st[j]));
    }
    *(bf16x8*)(qro + o) = ov;
  }
}

// ---------------- elementwise: ug = up * silu(gate) (silu applied in epilogue), overwrite up half ----------------
__global__ __launch_bounds__(256) void k_ew_ug(__hip_bfloat16* __restrict__ upg){
  size_t gid = (size_t)blockIdx.x*256 + threadIdx.x;
  size_t m = gid>>8; size_t l0 = (gid&255)*8;
  unsigned short* p = (unsigned short*)upg;
  bf16x8 uv = *(const bf16x8*)(p + m*4096 + l0);
  bf16x8 gv = *(const bf16x8*)(p + m*4096 + 2048 + l0);
  bf16x8 ov;
#pragma unroll
  for(int j=0;j<8;j++){
    float u = bf2f((unsigned short)uv[j]);
    float g = bf2f((unsigned short)gv[j]);
    ov[j] = (short)f2bf(u*g);
  }
  *(bf16x8*)(p + m*4096 + l0) = ov;
}

// ---------------- GEMM2: [Mc, 4096(readout|ug)] x [1024,4096]^T -> out fp32 ----------------
// BM=64 x BN=128 tile, 4 waves (2x2, wave tile 32x64) -> 2x block count vs 128^2,
// fixes the 1-block/CU latency-bound regime. Full-K loop, no atomics.

__global__ __launch_bounds__(256) void k_gemm2(const __hip_bfloat16* __restrict__ RO, const __hip_bfloat16* __restrict__ UPG,
    const __hip_bfloat16* __restrict__ B, float* __restrict__ out){
  __shared__ __hip_bfloat16 sA[64*32];
  __shared__ __hip_bfloat16 sB[128*32];
  int raw = blockIdx.x;
  int per = gridDim.x >> 3;
  int p = (raw & 7)*per + (raw >> 3);        // XCD-contiguous
  int group = p >> 6;                        // GROUP_M=8, nbn=8
  int rem = p & 63;
  int bm = group*8 + (rem & 7);
  int bn = rem >> 3;
  int t = threadIdx.x, w = t>>6, lane = t&63;
  int wr = w>>1, wc = w&1;

  f32x4 zero = {0.f,0.f,0.f,0.f};
  f32x4 acc[2][4];
#pragma unroll
  for(int i=0;i<2;i++)
#pragma unroll
    for(int j=0;j<4;j++) acc[i][j] = zero;

  const int frow = lane&15;
  const int kofs = (lane>>4)*8;
  const unsigned short* ROg  = (const unsigned short*)RO;
  const unsigned short* UPGg = (const unsigned short*)UPG;
  const unsigned short* Bg   = (const unsigned short*)B;

  for(int kt=0; kt<4096; kt+=32){
    const unsigned short* Abase; size_t ld; int kk;
    if(kt < 2048){ Abase = ROg;  ld = 2048; kk = kt; }
    else         { Abase = UPGg; ld = 4096; kk = kt - 2048; }
    // A tile 64x32 = 4KB = one 256-lane x 16B round
    gload16(Abase + (size_t)(bm*64 + (t>>2))*ld + kk + (t&3)*8, (char*)sA + (w*64)*16);
#pragma unroll
    for(int i=0;i<2;i++){
      int c = i*256 + t;
      gload16(Bg + (size_t)(bn*128 + (c>>2))*4096 + kt + (c&3)*8, (char*)sB + (i*256 + w*64)*16);
    }
    __syncthreads();
    bf16x8 af[2], bfr[4];
#pragma unroll
    for(int mi=0;mi<2;mi++) af[mi]  = *(const bf16x8*)&sA[(wr*32 + mi*16 + frow)*32 + kofs];
#pragma unroll
    for(int ni=0;ni<4;ni++) bfr[ni] = *(const bf16x8*)&sB[(wc*64 + ni*16 + frow)*32 + kofs];
#pragma unroll
    for(int mi=0;mi<2;mi++)
#pragma unroll
      for(int ni=0;ni<4;ni++)
        acc[mi][ni] = __builtin_amdgcn_mfma_f32_16x16x32_bf16(af[mi], bfr[ni], acc[mi][ni], 0,0,0);
    __syncthreads();
  }

  int row0 = bm*64 + wr*32 + ((lane>>4)<<2);
  int col0 = bn*128 + wc*64 + (lane&15);
#pragma unroll
  for(int mi=0;mi<2;mi++)
#pragma unroll
    for(int ni=0;ni<4;ni++)
#pragma unroll
      for(int j=0;j<4;j++)
        out[(size_t)(row0+mi*16+j)*1024 + col0 + ni*16] = acc[mi][ni][j];
}

// ---------------- launcher ----------------
extern "C" void kernel_launch(void* const* d_in, const int* in_sizes, int n_in,
                              void* d_out, int out_size, void* d_ws, size_t ws_size,
                              hipStream_t stream) {
  (void)in_sizes; (void)n_in; (void)out_size;
  const float* x   = (const float*)d_in[0];
  const float* Wf  = (const float*)d_in[1];
  const float* Wi  = (const float*)d_in[2];
  const float* Wv  = (const float*)d_in[3];
  const float* Wq  = (const float*)d_in[4];
  const float* Wro = (const float*)d_in[5];
  const float* Wu  = (const float*)d_in[6];
  const float* Wg  = (const float*)d_in[7];
  const float* Wd  = (const float*)d_in[8];
  const float* ist = (const float*)d_in[9];
  float* out = (float*)d_out;

  char* w = (char*)d_ws;
  auto alloc = [&](size_t bytes){ char* p = w; w += (bytes + 255) & ~(size_t)255; return p; };

  // fixed buffers (needed across the whole pipeline)
  __hip_bfloat16* xb = (__hip_bfloat16*)alloc(16777216);   // [8192][1024] bf16
  __hip_bfloat16* W1 = (__hip_bfloat16*)alloc(25165824);   // [12288][1024] bf16
  __hip_bfloat16* W2 = (__hip_bfloat16*)alloc(8388608);    // [1024][4096] bf16

  // choose batch-chunk size CB from available workspace (deterministic per env)
  size_t fixed = (size_t)16777216 + 25165824 + 8388608 + 3*256;
  // per-CB unit: fb f32 16M + gb,cb,qro bf16 3x8M + upg 16M + Fp/Sl/Ci 3x0.5M
  auto need = [&](int CBq)->size_t{
    return fixed + (size_t)CBq*((size_t)16777216 + 3*8388608 + 16777216 + 3*524288)
                 + 8*256 + (size_t)(1<<20);
  };
  int CB = (ws_size >= need(4)) ? 4 : (ws_size >= need(2)) ? 2 : 1;

  float* fb          = (float*)alloc((size_t)CB*16777216);          // tanh(f) f32
  unsigned short* gb = (unsigned short*)alloc((size_t)CB*8388608);  // sigmoid(g) bf16
  unsigned short* cb = (unsigned short*)alloc((size_t)CB*8388608);  // silu(c) bf16
  unsigned short* qro= (unsigned short*)alloc((size_t)CB*8388608);  // bf16 q -> readout
  __hip_bfloat16* upg= (__hip_bfloat16*)alloc((size_t)CB*16777216); // bf16 up|silu(gate)
  float* Fp = (float*)alloc((size_t)CB*524288);
  float* Sl = (float*)alloc((size_t)CB*524288);
  float* Ci = (float*)alloc((size_t)CB*524288);

  k_conv_x <<<4096, 256, 0, stream>>>(x, xb);
  k_conv_w1<<<6144, 256, 0, stream>>>(Wf, Wq, Wi, Wv, Wu, Wg, W1);
  k_conv_w2<<<2048, 256, 0, stream>>>(Wro, Wd, W2);

  for(int b0 = 0; b0 < 4; b0 += CB){
    k_gemm1<<<CB*16*96, 256, 0, stream>>>(xb + (size_t)b0*2048*1024, W1, fb,
                                          (__hip_bfloat16*)gb, (__hip_bfloat16*)cb,
                                          (__hip_bfloat16*)qro, upg);
    k_scanA<<<CB*64,   256, 0, stream>>>(fb, gb, cb, Fp, Sl);
    k_scanB<<<CB*8,    256, 0, stream>>>(Fp, Sl, ist, Ci);
    k_scanC<<<CB*64,   256, 0, stream>>>(fb, gb, cb, qro, Ci);
    k_ew_ug<<<CB*2048, 256, 0, stream>>>(upg);
    k_gemm2<<<CB*32*8, 256, 0, stream>>>((const __hip_bfloat16*)qro, upg, W2,
                                         out + (size_t)b0*2048*1024);
  }
}

// Round 6
// 639.335 us; speedup vs baseline: 1.1302x; 1.0251x over previous
//
#include <hip/hip_runtime.h>
#include <hip/hip_bf16.h>

typedef __attribute__((ext_vector_type(8))) short bf16x8;   // 8 bf16 in 4 VGPRs
typedef __attribute__((ext_vector_type(4))) float f32x4;

#define DEV __device__ __forceinline__

DEV float fsigmoid(float x){ return 1.0f/(1.0f + __expf(-x)); }
DEV float fsilu(float x){ return x/(1.0f + __expf(-x)); }
DEV float ftanh(float x){ return 1.0f - 2.0f/(1.0f + __expf(2.0f*x)); }

DEV unsigned short f2bf(float x){
  __hip_bfloat16 h = __float2bfloat16(x);
  return *reinterpret_cast<unsigned short*>(&h);
}
DEV float bf2f(unsigned short u){ return __uint_as_float(((unsigned)u) << 16); }

typedef const __attribute__((address_space(1))) unsigned int* gas_ptr;
typedef __attribute__((address_space(3))) unsigned int* las_ptr;
// async global->LDS, 16B/lane; LDS dest = wave-uniform base, HW adds lane*16.
DEV void gload16(const void* gp, void* lp){
  __builtin_amdgcn_global_load_lds((gas_ptr)gp, (las_ptr)lp, 16, 0, 0);
}

// ---------------- conversion kernels ----------------

__global__ __launch_bounds__(256) void k_conv_x(const float* __restrict__ src, __hip_bfloat16* __restrict__ dst){
  size_t gid = (size_t)blockIdx.x*256 + threadIdx.x;
  size_t base = gid*8;
  f32x4 a = *(const f32x4*)(src+base);
  f32x4 b = *(const f32x4*)(src+base+4);
  bf16x8 o;
#pragma unroll
  for(int j=0;j<4;j++){ o[j]=(short)f2bf(a[j]); o[4+j]=(short)f2bf(b[j]); }
  *(bf16x8*)((unsigned short*)dst + base) = o;
}

// W1 rows: [0:2048)=W_forget, [2048:4096)=W_query, [4096:6144)=W_input,
//          [6144:8192)=W_value, [8192:10240)=W_up, [10240:12288)=W_gate
__global__ __launch_bounds__(256) void k_conv_w1(const float* __restrict__ Wf,const float* __restrict__ Wq,
    const float* __restrict__ Wi,const float* __restrict__ Wv,const float* __restrict__ Wu,
    const float* __restrict__ Wg, __hip_bfloat16* __restrict__ W1){
  int gid = blockIdx.x*256 + threadIdx.x;
  int row = gid>>7; int col = (gid&127)*8;
  int seg = row>>11; int sr = row & 2047;
  const float* s;
  if(seg==0)s=Wf; else if(seg==1)s=Wq; else if(seg==2)s=Wi; else if(seg==3)s=Wv; else if(seg==4)s=Wu; else s=Wg;
  const float* p = s + (size_t)sr*1024 + col;
  f32x4 a = *(const f32x4*)p; f32x4 b = *(const f32x4*)(p+4);
  bf16x8 o;
#pragma unroll
  for(int j=0;j<4;j++){ o[j]=(short)f2bf(a[j]); o[4+j]=(short)f2bf(b[j]); }
  *(bf16x8*)((unsigned short*)W1 + (size_t)row*1024 + col) = o;
}

// W2 [1024][4096]: cols [0:2048)=W_rec_out row, [2048:4096)=W_down row
__global__ __launch_bounds__(256) void k_conv_w2(const float* __restrict__ Wro, const float* __restrict__ Wd,
    __hip_bfloat16* __restrict__ W2){
  int gid = blockIdx.x*256 + threadIdx.x;
  int row = gid>>9; int col = (gid&511)*8;
  const float* p = (col<2048) ? (Wro + (size_t)row*2048 + col) : (Wd + (size_t)row*2048 + (col-2048));
  f32x4 a = *(const f32x4*)p; f32x4 b = *(const f32x4*)(p+4);
  bf16x8 o;
#pragma unroll
  for(int j=0;j<4;j++){ o[j]=(short)f2bf(a[j]); o[4+j]=(short)f2bf(b[j]); }
  *(bf16x8*)((unsigned short*)W2 + (size_t)row*4096 + col) = o;
}

// ---------------- GEMM1: [Mc,1024] x [12288,1024]^T, activation epilogue ----------------
// m97 structure: 128x128 tile, BK=32, 4 waves (2x2), 16x16x32 bf16 MFMA, global_load_lds w16.
// Block ordering: XCD-chunked + GROUP_M=8 column-major-in-group for L2 locality.

__global__ __launch_bounds__(256) void k_gemm1(const __hip_bfloat16* __restrict__ A, const __hip_bfloat16* __restrict__ B,
    float* __restrict__ fb, __hip_bfloat16* __restrict__ gb, __hip_bfloat16* __restrict__ cb,
    __hip_bfloat16* __restrict__ qb, __hip_bfloat16* __restrict__ upg){
  const int K = 1024;
  __shared__ __hip_bfloat16 sA[128*32];
  __shared__ __hip_bfloat16 sB[128*32];
  const int NBN = 96;
  int raw = blockIdx.x;
  int per = gridDim.x >> 3;                  // grid %8==0 in all CB configs
  int p = (raw & 7)*per + (raw >> 3);        // XCD-contiguous position
  int group = p / (8*NBN);                   // nbm %8==0 for CB in {1,2,4}
  int rem   = p % (8*NBN);
  int bm = group*8 + (rem & 7);              // column-major within 8-row group
  int bn = rem >> 3;
  int t = threadIdx.x, w = t>>6, lane = t&63;
  int wr = w>>1, wc = w&1;

  f32x4 zero = {0.f,0.f,0.f,0.f};
  f32x4 acc[4][4];
#pragma unroll
  for(int i=0;i<4;i++)
#pragma unroll
    for(int j=0;j<4;j++) acc[i][j] = zero;

  const int frow = lane&15;
  const int kofs = (lane>>4)*8;
  const unsigned short* Ag = (const unsigned short*)A;
  const unsigned short* Bg = (const unsigned short*)B;

  for(int kt=0; kt<K; kt+=32){
#pragma unroll
    for(int i=0;i<2;i++){
      int c = i*256 + t;
      gload16(Ag + (size_t)(bm*128 + (c>>2))*K + kt + (c&3)*8, (char*)sA + (i*256 + w*64)*16);
      gload16(Bg + (size_t)(bn*128 + (c>>2))*K + kt + (c&3)*8, (char*)sB + (i*256 + w*64)*16);
    }
    __syncthreads();
    bf16x8 af[4], bfr[4];
#pragma unroll
    for(int mi=0;mi<4;mi++) af[mi]  = *(const bf16x8*)&sA[(wr*64 + mi*16 + frow)*32 + kofs];
#pragma unroll
    for(int ni=0;ni<4;ni++) bfr[ni] = *(const bf16x8*)&sB[(wc*64 + ni*16 + frow)*32 + kofs];
#pragma unroll
    for(int mi=0;mi<4;mi++)
#pragma unroll
      for(int ni=0;ni<4;ni++)
        acc[mi][ni] = __builtin_amdgcn_mfma_f32_16x16x32_bf16(af[mi], bfr[ni], acc[mi][ni], 0,0,0);
    __syncthreads();
  }

  // epilogue: C/D layout col=lane&15, row=(lane>>4)*4+j  [m89-verified]
  int seg = bn/16;                                  // 16 n-tiles per 2048-col segment
  int row0 = bm*128 + wr*64 + ((lane>>4)<<2);
  int colL = ((bn*128)&2047) + wc*64 + (lane&15);

#define EPI(STMT) \
  _Pragma("unroll") for(int mi=0;mi<4;mi++) \
  _Pragma("unroll") for(int ni=0;ni<4;ni++) \
  _Pragma("unroll") for(int j=0;j<4;j++) { \
    int rr=row0+mi*16+j; int cc=colL+ni*16; float v=acc[mi][ni][j]; STMT; }

  if(seg==0)      { EPI( fb[(size_t)rr*2048+cc] = ftanh(v) ) }
  else if(seg==1) { EPI( qb[(size_t)rr*2048+cc] = __float2bfloat16(v) ) }
  else if(seg==2) { EPI( gb[(size_t)rr*2048+cc] = __float2bfloat16(fsigmoid(v)) ) }
  else if(seg==3) { EPI( cb[(size_t)rr*2048+cc] = __float2bfloat16(fsilu(v)) ) }
  else if(seg==4) { EPI( upg[(size_t)rr*4096+cc] = __float2bfloat16(v) ) }
  else            { EPI( upg[(size_t)rr*4096+2048+cc] = __float2bfloat16(fsilu(v)) ) }
#undef EPI
}

// ---------------- scan: 3-pass chunked diagonal recurrence ----------------
#define NC 64
#define CHL 32

__global__ __launch_bounds__(256) void k_scanA(const float* __restrict__ f_, const unsigned short* __restrict__ g_,
    const unsigned short* __restrict__ c_, float* __restrict__ Fp_, float* __restrict__ Sl_){
  int blk = blockIdx.x; int b = blk>>6; int ch = blk&63;   // b chunk-local
  int r0 = threadIdx.x*8;
  float st[8], Fp[8];
#pragma unroll
  for(int j=0;j<8;j++){ st[j]=0.f; Fp[j]=1.f; }
  size_t base = ((size_t)(b*2048 + ch*CHL))*2048 + r0;
#pragma unroll 4
  for(int s=0;s<CHL;s++){
    size_t o = base + (size_t)s*2048;
    float fv[8];
    *(f32x4*)&fv[0]=*(const f32x4*)(f_+o); *(f32x4*)&fv[4]=*(const f32x4*)(f_+o+4);
    bf16x8 gv8 = *(const bf16x8*)(g_+o);
    bf16x8 cv8 = *(const bf16x8*)(c_+o);
#pragma unroll
    for(int j=0;j<8;j++){
      float gc = bf2f((unsigned short)gv8[j]) * bf2f((unsigned short)cv8[j]);
      st[j] = fv[j]*st[j] + gc; Fp[j] *= fv[j];
    }
  }
  size_t so = ((size_t)blk)*2048 + r0;
  *(f32x4*)(Fp_+so)   = *(f32x4*)&Fp[0]; *(f32x4*)(Fp_+so+4) = *(f32x4*)&Fp[4];
  *(f32x4*)(Sl_+so)   = *(f32x4*)&st[0]; *(f32x4*)(Sl_+so+4) = *(f32x4*)&st[4];
}

__global__ __launch_bounds__(256) void k_scanB(const float* __restrict__ Fp_, const float* __restrict__ Sl_,
    const float* __restrict__ init, float* __restrict__ Cin_){
  int gid = blockIdx.x*256 + threadIdx.x;   // CB*2048 threads
  int b = gid>>11; int r = gid&2047;
  float carry = init[r];
  for(int ch=0; ch<NC; ch++){
    size_t o = ((size_t)(b*NC+ch))*2048 + r;
    Cin_[o] = carry;
    carry = Fp_[o]*carry + Sl_[o];
  }
}

// q read (bf16) and readout write share the SAME buffer (qro): element o is read
// then overwritten by the same thread — race-free; no __restrict__ on qro.
__global__ __launch_bounds__(256) void k_scanC(const float* __restrict__ f_, const unsigned short* __restrict__ g_,
    const unsigned short* __restrict__ c_, unsigned short* qro, const float* __restrict__ Cin_){
  int blk = blockIdx.x; int b = blk>>6; int ch = blk&63;
  int r0 = threadIdx.x*8;
  float st[8];
  size_t so = ((size_t)blk)*2048 + r0;
  *(f32x4*)&st[0] = *(const f32x4*)(Cin_+so);
  *(f32x4*)&st[4] = *(const f32x4*)(Cin_+so+4);
  size_t base = ((size_t)(b*2048 + ch*CHL))*2048 + r0;
#pragma unroll 2
  for(int s=0;s<CHL;s++){
    size_t o = base + (size_t)s*2048;
    float fv[8];
    *(f32x4*)&fv[0]=*(const f32x4*)(f_+o); *(f32x4*)&fv[4]=*(const f32x4*)(f_+o+4);
    bf16x8 gv8 = *(const bf16x8*)(g_+o);
    bf16x8 cv8 = *(const bf16x8*)(c_+o);
    bf16x8 qu = *(const bf16x8*)(qro + o);
    bf16x8 ov;
#pragma unroll
    for(int j=0;j<8;j++){
      float gc = bf2f((unsigned short)gv8[j]) * bf2f((unsigned short)cv8[j]);
      st[j] = fv[j]*st[j] + gc;
      float qv = bf2f((unsigned short)qu[j]);
      ov[j] = (short)f2bf(fsilu(qv*st[j]));
    }
    *(bf16x8*)(qro + o) = ov;
  }
}

// ---------------- elementwise: ug = up * silu(gate) (silu applied in epilogue), overwrite up half ----------------
__global__ __launch_bounds__(256) void k_ew_ug(__hip_bfloat16* __restrict__ upg){
  size_t gid = (size_t)blockIdx.x*256 + threadIdx.x;
  size_t m = gid>>8; size_t l0 = (gid&255)*8;
  unsigned short* p = (unsigned short*)upg;
  bf16x8 uv = *(const bf16x8*)(p + m*4096 + l0);
  bf16x8 gv = *(const bf16x8*)(p + m*4096 + 2048 + l0);
  bf16x8 ov;
#pragma unroll
  for(int j=0;j<8;j++){
    float u = bf2f((unsigned short)uv[j]);
    float g = bf2f((unsigned short)gv[j]);
    ov[j] = (short)f2bf(u*g);
  }
  *(bf16x8*)(p + m*4096 + l0) = ov;
}

// ---------------- GEMM2: [Mc, 4096(readout|ug)] x [1024,4096]^T -> out fp32 ----------------
// Wave-split-K 128x128 tile, 8 waves (512 threads): waves 0-3 compute the RO half
// (K=0:2048), waves 4-7 the UPG half concurrently (independent LDS staging buffers,
// same k-step body as k_gemm1: 16 MFMA per 2 barriers per group). fp32 LDS reduce.

__global__ __launch_bounds__(512) void k_gemm2(const __hip_bfloat16* __restrict__ RO, const __hip_bfloat16* __restrict__ UPG,
    const __hip_bfloat16* __restrict__ B, float* __restrict__ out){
  __shared__ __hip_bfloat16 sA[2][128*32];
  __shared__ __hip_bfloat16 sB[2][128*32];
  __shared__ float red[128][132];            // +4 pad: 4-row lane groups hit disjoint banks
  int raw = blockIdx.x;
  int per = gridDim.x >> 3;
  int p = (raw & 7)*per + (raw >> 3);        // XCD-contiguous
  int bm = p >> 3, bn = p & 7;
  int t = threadIdx.x;
  int g  = t >> 8;                           // K-half group: 0=RO, 1=UPG
  int tl = t & 255;                          // thread-in-group
  int wl = tl >> 6;                          // wave-in-group 0..3
  int lane = t & 63;
  int wr = wl >> 1, wc = wl & 1;

  f32x4 zero = {0.f,0.f,0.f,0.f};
  f32x4 acc[4][4];
#pragma unroll
  for(int i=0;i<4;i++)
#pragma unroll
    for(int j=0;j<4;j++) acc[i][j] = zero;

  const int frow = lane&15;
  const int kofs = (lane>>4)*8;
  // group 0: A = RO [Mc][2048], B cols 0:2048.  group 1: A = UPG [Mc][4096] (ug in cols 0:2048), B cols 2048:4096.
  const unsigned short* Agrp = (g==0) ? (const unsigned short*)RO : (const unsigned short*)UPG;
  const size_t ldA = (g==0) ? 2048 : 4096;
  const unsigned short* Bgrp = (const unsigned short*)B + g*2048;   // row stride 4096
  __hip_bfloat16* mysA = sA[g];
  __hip_bfloat16* mysB = sB[g];

  for(int kt=0; kt<2048; kt+=32){
#pragma unroll
    for(int i=0;i<2;i++){
      int c = i*256 + tl;
      gload16(Agrp + (size_t)(bm*128 + (c>>2))*ldA + kt + (c&3)*8, (char*)mysA + (i*256 + wl*64)*16);
      gload16(Bgrp + (size_t)(bn*128 + (c>>2))*4096 + kt + (c&3)*8, (char*)mysB + (i*256 + wl*64)*16);
    }
    __syncthreads();
    bf16x8 af[4], bfr[4];
#pragma unroll
    for(int mi=0;mi<4;mi++) af[mi]  = *(const bf16x8*)&mysA[(wr*64 + mi*16 + frow)*32 + kofs];
#pragma unroll
    for(int ni=0;ni<4;ni++) bfr[ni] = *(const bf16x8*)&mysB[(wc*64 + ni*16 + frow)*32 + kofs];
#pragma unroll
    for(int mi=0;mi<4;mi++)
#pragma unroll
      for(int ni=0;ni<4;ni++)
        acc[mi][ni] = __builtin_amdgcn_mfma_f32_16x16x32_bf16(af[mi], bfr[ni], acc[mi][ni], 0,0,0);
    __syncthreads();
  }

  // reduce: group1 -> LDS, barrier, group0 adds and stores. C/D: col=lane&15, row=(lane>>4)*4+j.
  int rloc0 = wr*64 + ((lane>>4)<<2);
  int cloc  = wc*64 + (lane&15);
  if(g==1){
#pragma unroll
    for(int mi=0;mi<4;mi++)
#pragma unroll
      for(int ni=0;ni<4;ni++)
#pragma unroll
        for(int j=0;j<4;j++)
          red[rloc0 + mi*16 + j][cloc + ni*16] = acc[mi][ni][j];
  }
  __syncthreads();
  if(g==0){
    int row0 = bm*128 + rloc0;
    int col0 = bn*128 + cloc;
#pragma unroll
    for(int mi=0;mi<4;mi++)
#pragma unroll
      for(int ni=0;ni<4;ni++)
#pragma unroll
        for(int j=0;j<4;j++)
          out[(size_t)(row0+mi*16+j)*1024 + col0 + ni*16] =
            acc[mi][ni][j] + red[rloc0 + mi*16 + j][cloc + ni*16];
  }
}

// ---------------- launcher ----------------
extern "C" void kernel_launch(void* const* d_in, const int* in_sizes, int n_in,
                              void* d_out, int out_size, void* d_ws, size_t ws_size,
                              hipStream_t stream) {
  (void)in_sizes; (void)n_in; (void)out_size;
  const float* x   = (const float*)d_in[0];
  const float* Wf  = (const float*)d_in[1];
  const float* Wi  = (const float*)d_in[2];
  const float* Wv  = (const float*)d_in[3];
  const float* Wq  = (const float*)d_in[4];
  const float* Wro = (const float*)d_in[5];
  const float* Wu  = (const float*)d_in[6];
  const float* Wg  = (const float*)d_in[7];
  const float* Wd  = (const float*)d_in[8];
  const float* ist = (const float*)d_in[9];
  float* out = (float*)d_out;

  char* w = (char*)d_ws;
  auto alloc = [&](size_t bytes){ char* p = w; w += (bytes + 255) & ~(size_t)255; return p; };

  // fixed buffers (needed across the whole pipeline)
  __hip_bfloat16* xb = (__hip_bfloat16*)alloc(16777216);   // [8192][1024] bf16
  __hip_bfloat16* W1 = (__hip_bfloat16*)alloc(25165824);   // [12288][1024] bf16
  __hip_bfloat16* W2 = (__hip_bfloat16*)alloc(8388608);    // [1024][4096] bf16

  // choose batch-chunk size CB from available workspace (deterministic per env)
  size_t fixed = (size_t)16777216 + 25165824 + 8388608 + 3*256;
  // per-CB unit: fb f32 16M + gb,cb,qro bf16 3x8M + upg 16M + Fp/Sl/Ci 3x0.5M
  auto need = [&](int CBq)->size_t{
    return fixed + (size_t)CBq*((size_t)16777216 + 3*8388608 + 16777216 + 3*524288)
                 + 8*256 + (size_t)(1<<20);
  };
  int CB = (ws_size >= need(4)) ? 4 : (ws_size >= need(2)) ? 2 : 1;

  float* fb          = (float*)alloc((size_t)CB*16777216);          // tanh(f) f32
  unsigned short* gb = (unsigned short*)alloc((size_t)CB*8388608);  // sigmoid(g) bf16
  unsigned short* cb = (unsigned short*)alloc((size_t)CB*8388608);  // silu(c) bf16
  unsigned short* qro= (unsigned short*)alloc((size_t)CB*8388608);  // bf16 q -> readout
  __hip_bfloat16* upg= (__hip_bfloat16*)alloc((size_t)CB*16777216); // bf16 up|silu(gate)
  float* Fp = (float*)alloc((size_t)CB*524288);
  float* Sl = (float*)alloc((size_t)CB*524288);
  float* Ci = (float*)alloc((size_t)CB*524288);

  k_conv_x <<<4096, 256, 0, stream>>>(x, xb);
  k_conv_w1<<<6144, 256, 0, stream>>>(Wf, Wq, Wi, Wv, Wu, Wg, W1);
  k_conv_w2<<<2048, 256, 0, stream>>>(Wro, Wd, W2);

  for(int b0 = 0; b0 < 4; b0 += CB){
    k_gemm1<<<CB*16*96, 256, 0, stream>>>(xb + (size_t)b0*2048*1024, W1, fb,
                                          (__hip_bfloat16*)gb, (__hip_bfloat16*)cb,
                                          (__hip_bfloat16*)qro, upg);
    k_scanA<<<CB*64,   256, 0, stream>>>(fb, gb, cb, Fp, Sl);
    k_scanB<<<CB*8,    256, 0, stream>>>(Fp, Sl, ist, Ci);
    k_scanC<<<CB*64,   256, 0, stream>>>(fb, gb, cb, qro, Ci);
    k_ew_ug<<<CB*2048, 256, 0, stream>>>(upg);
    k_gemm2<<<CB*16*8, 512, 0, stream>>>((const __hip_bfloat16*)qro, upg, W2,
                                         out + (size_t)b0*2048*1024);
  }
}